// Round 3
// baseline (339.466 us; speedup 1.0000x reference)
//
#include <hip/hip_runtime.h>

typedef unsigned short u16;
typedef unsigned int u32;
typedef __bf16 bf16x8 __attribute__((ext_vector_type(8)));
typedef float f32x4 __attribute__((ext_vector_type(4)));

#define MFMA16(a, b, c) __builtin_amdgcn_mfma_f32_16x16x32_bf16(a, b, c, 0, 0, 0)

static __device__ __forceinline__ u16 f2bf(float f) {
  union { float f; u32 u; } v; v.f = f;
  u32 u = v.u;
  u32 r = (u + 0x7FFFu + ((u >> 16) & 1u)) >> 16;  // RNE
  return (u16)r;
}

static __device__ __forceinline__ bf16x8 ld16(const u16* p) {
  return __builtin_bit_cast(bf16x8, *(const uint4*)p);
}

// ---------------------------------------------------------------------------
// K2a: transpose+cast  src [B][64][4096] f32  ->  dst [B][4096][64] bf16
// ---------------------------------------------------------------------------
__global__ __launch_bounds__(256) void transpose_cast(const float* __restrict__ src,
                                                      u16* __restrict__ dst) {
  __shared__ __align__(4) u16 tile[64 * 66];
  const int t = threadIdx.x;
  const int b = blockIdx.x >> 6;
  const int n0 = (blockIdx.x & 63) << 6;
  const float* sp = src + ((size_t)b << 18);
#pragma unroll
  for (int i = 0; i < 16; i++) {
    int d = (i << 2) + (t >> 6);
    int n = t & 63;
    tile[n * 66 + d] = f2bf(sp[((size_t)d << 12) + n0 + n]);
  }
  __syncthreads();
  u16* dp = dst + ((size_t)(b * 4096 + n0) << 6);
#pragma unroll
  for (int i = 0; i < 8; i++) {
    int n = (i << 3) + (t >> 5);
    int dp2 = t & 31;
    *(u32*)(dp + n * 64 + (dp2 << 1)) = *(const u32*)(tile + n * 66 + (dp2 << 1));
  }
}

// ---------------------------------------------------------------------------
// K2b: cast/pad weights.  W1 [128][131] -> W1b [128][160] bf16 (zero pad),
// W2 [128][128] -> W2b bf16.
// ---------------------------------------------------------------------------
__global__ __launch_bounds__(256) void prep_w(const float* __restrict__ W1,
                                              const float* __restrict__ W2,
                                              u16* __restrict__ W1b,
                                              u16* __restrict__ W2b) {
  int t = blockIdx.x * 256 + threadIdx.x;
  if (t < 128 * 160) {
    int r = t / 160, c = t - r * 160;
    W1b[t] = (c < 131) ? f2bf(W1[r * 131 + c]) : (u16)0;
  } else {
    int u = t - 128 * 160;
    W2b[u] = f2bf(W2[u]);
  }
}

// ---------------------------------------------------------------------------
// K1: KNN-16 replicating the np reference's fp32 arithmetic:
//   s1  = ((x^2 + y^2) + z^2)                       (fp32 mul+add, no FMA)
//   dot = fma(z,bz, fma(y,by, rn(x*bx)))            (BLAS-style FMA chain)
//   d2  = fl(fl(s1 + s2) - fl(2*dot))               (fp32)
// Ranking by these values, tie-break lowest index (lax.top_k semantics).
// ---------------------------------------------------------------------------
__global__ __launch_bounds__(256) void knn_kernel(const float* __restrict__ xyz1,
                                                  const float* __restrict__ xyz2,
                                                  int* __restrict__ knn) {
  __shared__ float dist[4096];
  __shared__ float hd[256];
  __shared__ int hm[256];
  __shared__ int sel;
  const int t = threadIdx.x;
  const int b = blockIdx.x >> 12;
  const int n = blockIdx.x & 4095;
  const float* X1 = xyz1 + b * 12288;
  const float* X2 = xyz2 + b * 12288;
  const float x = X1[n];
  const float y = X1[4096 + n];
  const float z = X1[8192 + n];
  const float s1 = __fadd_rn(__fadd_rn(__fmul_rn(x, x), __fmul_rn(y, y)),
                             __fmul_rn(z, z));

  float bd = 3e38f; int bm = 0;
#pragma unroll
  for (int j = 0; j < 16; j++) {
    int m = t + (j << 8);
    float bx = X2[m], by = X2[4096 + m], bz = X2[8192 + m];
    float s2 = __fadd_rn(__fadd_rn(__fmul_rn(bx, bx), __fmul_rn(by, by)),
                         __fmul_rn(bz, bz));
    // BLAS sgemm k-loop: acc=0; acc=fma(a_k,b_k,acc) ascending k
    float dt = __builtin_fmaf(z, bz, __builtin_fmaf(y, by, __fmul_rn(x, bx)));
    float d2 = __fsub_rn(__fadd_rn(s1, s2), __fmul_rn(2.0f, dt));
    dist[m] = d2;
    if (d2 < bd) { bd = d2; bm = m; }   // ascending m scan: strict < keeps lowest index
  }
  hd[t] = bd; hm[t] = bm;
  __syncthreads();

  for (int r = 0; r < 16; r++) {
    if (t < 64) {
      float d = hd[t * 4]; int m = hm[t * 4];
#pragma unroll
      for (int i = 1; i < 4; i++) {
        float di = hd[t * 4 + i]; int mi = hm[t * 4 + i];
        if (di < d || (di == d && mi < m)) { d = di; m = mi; }
      }
#pragma unroll
      for (int off = 32; off; off >>= 1) {
        float od = __shfl_down(d, off);
        int om = __shfl_down(m, off);
        if (od < d || (od == d && om < m)) { d = od; m = om; }
      }
      if (t == 0) {
        sel = m;
        dist[m] = 3e38f;
        knn[(((size_t)blockIdx.x) << 4) + r] = m;
      }
    }
    __syncthreads();
    int sm = sel;
    if ((sm & 255) == t) {
      float nd = 3e38f; int nm = 0;
#pragma unroll
      for (int j = 0; j < 16; j++) {
        int m = t + (j << 8);
        float d2 = dist[m];
        if (d2 < nd) { nd = d2; nm = m; }
      }
      hd[t] = nd; hm[t] = nm;
    }
    __syncthreads();
  }
}

// ---------------------------------------------------------------------------
// K3: fused gather + MLP (bf16 MFMA) + inverse-distance weighted reduce.
// 8 query rows per block -> M = 128 k-points.  F in LDS [128][168] bf16.
// H1 overwrites F cols 0..127 (each wave owns its 32 rows end-to-end).
// ---------------------------------------------------------------------------
__global__ __launch_bounds__(256) void mlp_kernel(
    const float* __restrict__ xyz1, const float* __restrict__ xyz2,
    const u16* __restrict__ p1t, const u16* __restrict__ p2t,
    const int* __restrict__ knn,
    const u16* __restrict__ W1b, const float* __restrict__ b1,
    const u16* __restrict__ W2b, const float* __restrict__ b2,
    float* __restrict__ out) {
  __shared__ __align__(16) u16 F[128 * 168];
  __shared__ __align__(16) float winv[128];
  __shared__ __align__(16) float wnorm[128];
  __shared__ __align__(16) float outbuf[128 * 12];
  const int t = threadIdx.x;
  const int g = blockIdx.x;
  const int b = g >> 9;
  const int rbase = (g & 511) << 3;

  // ---- Phase A: build F = [p1 | p2[idx] | dir | 0-pad] --------------------
  {
    const int m = t >> 1, half = t & 1;
    const int n1 = rbase + (m >> 4);
    const uint4* s1p = (const uint4*)(p1t + ((size_t)(b * 4096 + n1) << 6)) + half * 4;
    uint4* d1p = (uint4*)(F + m * 168) + half * 4;
    d1p[0] = s1p[0]; d1p[1] = s1p[1]; d1p[2] = s1p[2]; d1p[3] = s1p[3];
    const int idx = knn[(((size_t)(b * 4096 + n1)) << 4) + (m & 15)];
    const uint4* s2p = (const uint4*)(p2t + ((size_t)(b * 4096 + idx) << 6)) + half * 4;
    uint4* d2p = (uint4*)(F + m * 168 + 64) + half * 4;
    d2p[0] = s2p[0]; d2p[1] = s2p[1]; d2p[2] = s2p[2]; d2p[3] = s2p[3];
  }
  if (t < 128) {
    const int m = t;
    const int n1 = rbase + (m >> 4);
    const int idx = knn[(((size_t)(b * 4096 + n1)) << 4) + (m & 15)];
    const float* X1 = xyz1 + b * 12288;
    const float* X2 = xyz2 + b * 12288;
    float dx = X2[idx] - X1[n1];
    float dy = X2[4096 + idx] - X1[4096 + n1];
    float dz = X2[8192 + idx] - X1[8192 + n1];
    u32 u0 = (u32)f2bf(dx) | ((u32)f2bf(dy) << 16);
    u32 u1 = (u32)f2bf(dz);
    uint4 pk = make_uint4(u0, u1, 0u, 0u);
    *(uint4*)(F + m * 168 + 128) = pk;
    float d = sqrtf(dx * dx + dy * dy + dz * dz);
    winv[m] = 1.0f / fmaxf(d, 1e-10f);
  } else {
    const int m = t - 128;
    uint4 zz = make_uint4(0u, 0u, 0u, 0u);
    uint4* zp = (uint4*)(F + m * 168 + 136);
    zp[0] = zz; zp[1] = zz; zp[2] = zz; zp[3] = zz;
  }
  __syncthreads();
  if (t < 128) {
    const int r = t >> 4;
    float s = 0.f;
#pragma unroll
    for (int k = 0; k < 16; k++) s += winv[(r << 4) + k];
    wnorm[t] = winv[t] / s;
  }
  __syncthreads();

  const int lane = t & 63;
  const int wid = t >> 6;
  const int l15 = lane & 15;
  const int quad = lane >> 4;
  const int koff = quad << 3;

  const u16* Fr0 = F + (wid * 32 + l15) * 168 + koff;
  const u16* Fr1 = Fr0 + 16 * 168;

  // ---- GEMM1: [128x160] x W1b^T -> H1 [128x128] ---------------------------
  f32x4 acc[2][8];
  const f32x4 z4 = {0.f, 0.f, 0.f, 0.f};
#pragma unroll
  for (int i = 0; i < 2; i++)
#pragma unroll
    for (int j = 0; j < 8; j++) acc[i][j] = z4;

#pragma unroll
  for (int s = 0; s < 5; s++) {
    bf16x8 a0 = ld16(Fr0 + s * 32);
    bf16x8 a1 = ld16(Fr1 + s * 32);
#pragma unroll
    for (int nt = 0; nt < 8; nt++) {
      bf16x8 bf = ld16(W1b + (nt * 16 + l15) * 160 + s * 32 + koff);
      acc[0][nt] = MFMA16(a0, bf, acc[0][nt]);
      acc[1][nt] = MFMA16(a1, bf, acc[1][nt]);
    }
  }
#pragma unroll
  for (int nt = 0; nt < 8; nt++) {
    const float bv = b1[nt * 16 + l15];
#pragma unroll
    for (int mt = 0; mt < 2; mt++) {
      u16* hrow = F + (wid * 32 + mt * 16 + quad * 4) * 168 + nt * 16 + l15;
#pragma unroll
      for (int r = 0; r < 4; r++) {
        float zv = acc[mt][nt][r] + bv;
        zv = (zv >= 0.f) ? zv : 0.1f * zv;
        hrow[r * 168] = f2bf(zv);
      }
    }
  }
  __syncthreads();

  // ---- GEMM2: H1 [128x128] x W2b^T ---------------------------------------
  f32x4 acc2[2][8];
#pragma unroll
  for (int i = 0; i < 2; i++)
#pragma unroll
    for (int j = 0; j < 8; j++) acc2[i][j] = z4;

#pragma unroll
  for (int s = 0; s < 4; s++) {
    bf16x8 a0 = ld16(Fr0 + s * 32);
    bf16x8 a1 = ld16(Fr1 + s * 32);
#pragma unroll
    for (int nt = 0; nt < 8; nt++) {
      bf16x8 bf = ld16(W2b + (nt * 16 + l15) * 128 + s * 32 + koff);
      acc2[0][nt] = MFMA16(a0, bf, acc2[0][nt]);
      acc2[1][nt] = MFMA16(a1, bf, acc2[1][nt]);
    }
  }
  // ---- epilogue: leaky + bias, weighted sum over k, transpose via LDS -----
#pragma unroll
  for (int mt = 0; mt < 2; mt++) {
    const int mrow = wid * 2 + mt;
    const f32x4 w4 = *(const f32x4*)&wnorm[(mrow << 4) + (quad << 2)];
#pragma unroll
    for (int nt = 0; nt < 8; nt++) {
      const float bv = b2[nt * 16 + l15];
      float p = 0.f;
#pragma unroll
      for (int r = 0; r < 4; r++) {
        float zv = acc2[mt][nt][r] + bv;
        zv = (zv >= 0.f) ? zv : 0.1f * zv;
        p += zv * w4[r];
      }
      p += __shfl_xor(p, 16);
      p += __shfl_xor(p, 32);
      if (quad == 0) outbuf[(nt * 16 + l15) * 12 + mrow] = p;
    }
  }
  __syncthreads();
  {
    const int ch = t >> 1, half = t & 1;
    f32x4 v = *(const f32x4*)&outbuf[ch * 12 + (half << 2)];
    float* op = out + (((size_t)(b * 128 + ch)) << 12) + rbase + (half << 2);
    *(f32x4*)op = v;
  }
}

// ---------------------------------------------------------------------------
extern "C" void kernel_launch(void* const* d_in, const int* in_sizes, int n_in,
                              void* d_out, int out_size, void* d_ws, size_t ws_size,
                              hipStream_t stream) {
  const float* xyz1 = (const float*)d_in[0];
  const float* xyz2 = (const float*)d_in[1];
  const float* points1 = (const float*)d_in[2];
  const float* points2 = (const float*)d_in[3];
  const float* W1 = (const float*)d_in[4];
  const float* b1 = (const float*)d_in[5];
  const float* W2 = (const float*)d_in[6];
  const float* b2 = (const float*)d_in[7];
  float* out = (float*)d_out;

  char* ws = (char*)d_ws;
  int* knn = (int*)ws;                        // 16384*16*4      = 1,048,576 B
  u16* p1t = (u16*)(ws + 1048576);            // 2,097,152 B
  u16* p2t = (u16*)(ws + 3145728);            // 2,097,152 B
  u16* W1b = (u16*)(ws + 5242880);            // 40,960 B
  u16* W2b = (u16*)(ws + 5283840);            // 32,768 B

  hipLaunchKernelGGL(transpose_cast, dim3(256), dim3(256), 0, stream, points1, p1t);
  hipLaunchKernelGGL(transpose_cast, dim3(256), dim3(256), 0, stream, points2, p2t);
  hipLaunchKernelGGL(prep_w, dim3(144), dim3(256), 0, stream, W1, W2, W1b, W2b);
  hipLaunchKernelGGL(knn_kernel, dim3(16384), dim3(256), 0, stream, xyz1, xyz2, knn);
  hipLaunchKernelGGL(mlp_kernel, dim3(2048), dim3(256), 0, stream,
                     xyz1, xyz2, p1t, p2t, knn, W1b, b1, W2b, b2, out);
}

// Round 4
// 315.756 us; speedup vs baseline: 1.0751x; 1.0751x over previous
//
#include <hip/hip_runtime.h>

typedef unsigned short u16;
typedef unsigned int u32;
typedef unsigned long long u64;
typedef __bf16 bf16x8 __attribute__((ext_vector_type(8)));
typedef float f32x4 __attribute__((ext_vector_type(4)));

#define MFMA16(a, b, c) __builtin_amdgcn_mfma_f32_16x16x32_bf16(a, b, c, 0, 0, 0)

static __device__ __forceinline__ u16 f2bf(float f) {
  union { float f; u32 u; } v; v.f = f;
  u32 u = v.u;
  u32 r = (u + 0x7FFFu + ((u >> 16) & 1u)) >> 16;  // RNE
  return (u16)r;
}

static __device__ __forceinline__ bf16x8 ld16(const u16* p) {
  return __builtin_bit_cast(bf16x8, *(const uint4*)p);
}

static __device__ __forceinline__ u64 u64min(u64 a, u64 b) { return a < b ? a : b; }

// In-wave bitonic sort of 64 u64 keys, ascending by lane. 21 compare-exchange levels.
static __device__ __forceinline__ u64 bitonic64(u64 v, int lane) {
#pragma unroll
  for (int k = 2; k <= 64; k <<= 1) {
#pragma unroll
    for (int j = k >> 1; j > 0; j >>= 1) {
      u64 o = __shfl_xor(v, j, 64);
      bool up = ((lane & k) == 0);
      bool lower = ((lane & j) == 0);
      u64 mn = v < o ? v : o;
      u64 mx = v < o ? o : v;
      v = (lower == up) ? mn : mx;
    }
  }
  return v;
}

// ---------------------------------------------------------------------------
// K2a: transpose+cast  src [B][64][4096] f32  ->  dst [B][4096][64] bf16
// ---------------------------------------------------------------------------
__global__ __launch_bounds__(256) void transpose_cast(const float* __restrict__ src,
                                                      u16* __restrict__ dst) {
  __shared__ __align__(4) u16 tile[64 * 66];
  const int t = threadIdx.x;
  const int b = blockIdx.x >> 6;
  const int n0 = (blockIdx.x & 63) << 6;
  const float* sp = src + ((size_t)b << 18);
#pragma unroll
  for (int i = 0; i < 16; i++) {
    int d = (i << 2) + (t >> 6);
    int n = t & 63;
    tile[n * 66 + d] = f2bf(sp[((size_t)d << 12) + n0 + n]);
  }
  __syncthreads();
  u16* dp = dst + ((size_t)(b * 4096 + n0) << 6);
#pragma unroll
  for (int i = 0; i < 8; i++) {
    int n = (i << 3) + (t >> 5);
    int dp2 = t & 31;
    *(u32*)(dp + n * 64 + (dp2 << 1)) = *(const u32*)(tile + n * 66 + (dp2 << 1));
  }
}

// ---------------------------------------------------------------------------
// K2b: cast/pad weights.  W1 [128][131] -> W1b [128][160] bf16 (zero pad),
// W2 [128][128] -> W2b bf16.
// ---------------------------------------------------------------------------
__global__ __launch_bounds__(256) void prep_w(const float* __restrict__ W1,
                                              const float* __restrict__ W2,
                                              u16* __restrict__ W1b,
                                              u16* __restrict__ W2b) {
  int t = blockIdx.x * 256 + threadIdx.x;
  if (t < 128 * 160) {
    int r = t / 160, c = t - r * 160;
    W1b[t] = (c < 131) ? f2bf(W1[r * 131 + c]) : (u16)0;
  } else {
    int u = t - 128 * 160;
    W2b[u] = f2bf(W2[u]);
  }
}

// ---------------------------------------------------------------------------
// K1: wave-per-row KNN-16, zero barriers.
// Distance arithmetic identical (bit-exact) to the round-3 passing kernel:
//   s1/s2 = ((a^2+b^2)+c^2) rn;  dot = fma(z,bz,fma(y,by,mul(x,bx)));
//   d2 = fl(fl(s1+s2) - fl(2*dot)).
// Order: packed u64 (monotone_u32(d2) << 32 | m) ascending — exact
// lowest-index tie-break, same total order as before.
// Selection: per-lane top-1 over its 64 contiguous candidates ->
// bitonic-64 of lane heads -> tau = 16th head (provable upper bound on the
// global 16th) -> compact candidates <= tau to LDS (provably <= 1024,
// typically ~20) -> bitonic-64 of survivors -> lanes 0..15 store.
// ---------------------------------------------------------------------------
__global__ __launch_bounds__(256, 4) void knn_kernel(const float* __restrict__ xyz1,
                                                     const float* __restrict__ xyz2,
                                                     int* __restrict__ knn) {
  __shared__ u64 surv[4][1024];
  __shared__ u32 cnt[4];
  const int t = threadIdx.x;
  const int lane = t & 63;
  const int w = t >> 6;
  const int row = blockIdx.x * 4 + w;  // 0..16383
  const int b = row >> 12;
  const int n = row & 4095;
  const float* X1 = xyz1 + b * 12288;
  const float* X2 = xyz2 + b * 12288;
  const float x = X1[n];
  const float y = X1[4096 + n];
  const float z = X1[8192 + n];
  const float s1 = __fadd_rn(__fadd_rn(__fmul_rn(x, x), __fmul_rn(y, y)),
                             __fmul_rn(z, z));

  u32 keys[64];
  u64 head = ~0ull;
  const int base = lane << 6;  // this lane's 64 contiguous candidates
#pragma unroll
  for (int j = 0; j < 16; j++) {
    f32x4 bx = *(const f32x4*)(X2 + base + j * 4);
    f32x4 by = *(const f32x4*)(X2 + 4096 + base + j * 4);
    f32x4 bz = *(const f32x4*)(X2 + 8192 + base + j * 4);
#pragma unroll
    for (int e = 0; e < 4; e++) {
      float s2 = __fadd_rn(__fadd_rn(__fmul_rn(bx[e], bx[e]), __fmul_rn(by[e], by[e])),
                           __fmul_rn(bz[e], bz[e]));
      float dt = __builtin_fmaf(z, bz[e], __builtin_fmaf(y, by[e], __fmul_rn(x, bx[e])));
      float d2 = __fsub_rn(__fadd_rn(s1, s2), __fmul_rn(2.0f, dt));
      u32 bb = __float_as_uint(d2);
      u32 sgn = (u32)((int)bb >> 31);
      u32 key = bb ^ (sgn | 0x80000000u);  // monotone total order for floats
      keys[j * 4 + e] = key;
      u64 k64 = ((u64)key << 32) | (u32)(base + j * 4 + e);
      head = head < k64 ? head : k64;
    }
  }

  // tau = 16th smallest lane-head (valid upper bound on global 16th)
  u64 hs = bitonic64(head, lane);
  u64 tau = __shfl(hs, 15, 64);

  // compact survivors (key64 <= tau) into per-wave LDS
  if (lane == 0) cnt[w] = 0;
#pragma unroll
  for (int j = 0; j < 64; j++) {
    u64 k64 = ((u64)keys[j] << 32) | (u32)(base + j);
    if (k64 <= tau) {
      u32 slot = atomicAdd(&cnt[w], 1u);
      surv[w][slot] = k64;  // order irrelevant: fully sorted below
    }
  }
  u32 S = cnt[w];  // same-wave LDS ops are in order: all adds visible

  if (S <= 64) {
    u64 v = (lane < (int)S) ? surv[w][lane] : ~0ull;
    v = bitonic64(v, lane);
    if (lane < 16) knn[row * 16 + lane] = (int)(v & 0xFFFFFFFFull);
  } else {
    // exact cold path (needs extreme candidate clustering; S <= 1024 provably)
    u64 mine[16];
#pragma unroll
    for (int k = 0; k < 16; k++) {
      int i = lane + (k << 6);
      mine[k] = (i < (int)S) ? surv[w][i] : ~0ull;
    }
    for (int r = 0; r < 16; r++) {
      u64 lm = mine[0];
#pragma unroll
      for (int k = 1; k < 16; k++) lm = u64min(lm, mine[k]);
      u64 gm = lm;
#pragma unroll
      for (int off = 32; off; off >>= 1) gm = u64min(gm, __shfl_xor(gm, off, 64));
      if (lane == 0) knn[row * 16 + r] = (int)(gm & 0xFFFFFFFFull);
#pragma unroll
      for (int k = 0; k < 16; k++)
        if (mine[k] == gm) mine[k] = ~0ull;
    }
  }
}

// ---------------------------------------------------------------------------
// K3: fused gather + MLP (bf16 MFMA) + inverse-distance weighted reduce.
// 8 query rows per block -> M = 128 k-points.  F in LDS [128][168] bf16.
// H1 overwrites F cols 0..127 (each wave owns its 32 rows end-to-end).
// ---------------------------------------------------------------------------
__global__ __launch_bounds__(256) void mlp_kernel(
    const float* __restrict__ xyz1, const float* __restrict__ xyz2,
    const u16* __restrict__ p1t, const u16* __restrict__ p2t,
    const int* __restrict__ knn,
    const u16* __restrict__ W1b, const float* __restrict__ b1,
    const u16* __restrict__ W2b, const float* __restrict__ b2,
    float* __restrict__ out) {
  __shared__ __align__(16) u16 F[128 * 168];
  __shared__ __align__(16) float winv[128];
  __shared__ __align__(16) float wnorm[128];
  __shared__ __align__(16) float outbuf[128 * 12];
  const int t = threadIdx.x;
  const int g = blockIdx.x;
  const int b = g >> 9;
  const int rbase = (g & 511) << 3;

  // ---- Phase A: build F = [p1 | p2[idx] | dir | 0-pad] --------------------
  {
    const int m = t >> 1, half = t & 1;
    const int n1 = rbase + (m >> 4);
    const uint4* s1p = (const uint4*)(p1t + ((size_t)(b * 4096 + n1) << 6)) + half * 4;
    uint4* d1p = (uint4*)(F + m * 168) + half * 4;
    d1p[0] = s1p[0]; d1p[1] = s1p[1]; d1p[2] = s1p[2]; d1p[3] = s1p[3];
    const int idx = knn[(((size_t)(b * 4096 + n1)) << 4) + (m & 15)];
    const uint4* s2p = (const uint4*)(p2t + ((size_t)(b * 4096 + idx) << 6)) + half * 4;
    uint4* d2p = (uint4*)(F + m * 168 + 64) + half * 4;
    d2p[0] = s2p[0]; d2p[1] = s2p[1]; d2p[2] = s2p[2]; d2p[3] = s2p[3];
  }
  if (t < 128) {
    const int m = t;
    const int n1 = rbase + (m >> 4);
    const int idx = knn[(((size_t)(b * 4096 + n1)) << 4) + (m & 15)];
    const float* X1 = xyz1 + b * 12288;
    const float* X2 = xyz2 + b * 12288;
    float dx = X2[idx] - X1[n1];
    float dy = X2[4096 + idx] - X1[4096 + n1];
    float dz = X2[8192 + idx] - X1[8192 + n1];
    u32 u0 = (u32)f2bf(dx) | ((u32)f2bf(dy) << 16);
    u32 u1 = (u32)f2bf(dz);
    uint4 pk = make_uint4(u0, u1, 0u, 0u);
    *(uint4*)(F + m * 168 + 128) = pk;
    float d = sqrtf(dx * dx + dy * dy + dz * dz);
    winv[m] = 1.0f / fmaxf(d, 1e-10f);
  } else {
    const int m = t - 128;
    uint4 zz = make_uint4(0u, 0u, 0u, 0u);
    uint4* zp = (uint4*)(F + m * 168 + 136);
    zp[0] = zz; zp[1] = zz; zp[2] = zz; zp[3] = zz;
  }
  __syncthreads();
  if (t < 128) {
    const int r = t >> 4;
    float s = 0.f;
#pragma unroll
    for (int k = 0; k < 16; k++) s += winv[(r << 4) + k];
    wnorm[t] = winv[t] / s;
  }
  __syncthreads();

  const int lane = t & 63;
  const int wid = t >> 6;
  const int l15 = lane & 15;
  const int quad = lane >> 4;
  const int koff = quad << 3;

  const u16* Fr0 = F + (wid * 32 + l15) * 168 + koff;
  const u16* Fr1 = Fr0 + 16 * 168;

  // ---- GEMM1: [128x160] x W1b^T -> H1 [128x128] ---------------------------
  f32x4 acc[2][8];
  const f32x4 z4 = {0.f, 0.f, 0.f, 0.f};
#pragma unroll
  for (int i = 0; i < 2; i++)
#pragma unroll
    for (int j = 0; j < 8; j++) acc[i][j] = z4;

#pragma unroll
  for (int s = 0; s < 5; s++) {
    bf16x8 a0 = ld16(Fr0 + s * 32);
    bf16x8 a1 = ld16(Fr1 + s * 32);
#pragma unroll
    for (int nt = 0; nt < 8; nt++) {
      bf16x8 bf = ld16(W1b + (nt * 16 + l15) * 160 + s * 32 + koff);
      acc[0][nt] = MFMA16(a0, bf, acc[0][nt]);
      acc[1][nt] = MFMA16(a1, bf, acc[1][nt]);
    }
  }
#pragma unroll
  for (int nt = 0; nt < 8; nt++) {
    const float bv = b1[nt * 16 + l15];
#pragma unroll
    for (int mt = 0; mt < 2; mt++) {
      u16* hrow = F + (wid * 32 + mt * 16 + quad * 4) * 168 + nt * 16 + l15;
#pragma unroll
      for (int r = 0; r < 4; r++) {
        float zv = acc[mt][nt][r] + bv;
        zv = (zv >= 0.f) ? zv : 0.1f * zv;
        hrow[r * 168] = f2bf(zv);
      }
    }
  }
  __syncthreads();

  // ---- GEMM2: H1 [128x128] x W2b^T ---------------------------------------
  f32x4 acc2[2][8];
#pragma unroll
  for (int i = 0; i < 2; i++)
#pragma unroll
    for (int j = 0; j < 8; j++) acc2[i][j] = z4;

#pragma unroll
  for (int s = 0; s < 4; s++) {
    bf16x8 a0 = ld16(Fr0 + s * 32);
    bf16x8 a1 = ld16(Fr1 + s * 32);
#pragma unroll
    for (int nt = 0; nt < 8; nt++) {
      bf16x8 bf = ld16(W2b + (nt * 16 + l15) * 128 + s * 32 + koff);
      acc2[0][nt] = MFMA16(a0, bf, acc2[0][nt]);
      acc2[1][nt] = MFMA16(a1, bf, acc2[1][nt]);
    }
  }
  // ---- epilogue: leaky + bias, weighted sum over k, transpose via LDS -----
#pragma unroll
  for (int mt = 0; mt < 2; mt++) {
    const int mrow = wid * 2 + mt;
    const f32x4 w4 = *(const f32x4*)&wnorm[(mrow << 4) + (quad << 2)];
#pragma unroll
    for (int nt = 0; nt < 8; nt++) {
      const float bv = b2[nt * 16 + l15];
      float p = 0.f;
#pragma unroll
      for (int r = 0; r < 4; r++) {
        float zv = acc2[mt][nt][r] + bv;
        zv = (zv >= 0.f) ? zv : 0.1f * zv;
        p += zv * w4[r];
      }
      p += __shfl_xor(p, 16);
      p += __shfl_xor(p, 32);
      if (quad == 0) outbuf[(nt * 16 + l15) * 12 + mrow] = p;
    }
  }
  __syncthreads();
  {
    const int ch = t >> 1, half = t & 1;
    f32x4 v = *(const f32x4*)&outbuf[ch * 12 + (half << 2)];
    float* op = out + (((size_t)(b * 128 + ch)) << 12) + rbase + (half << 2);
    *(f32x4*)op = v;
  }
}

// ---------------------------------------------------------------------------
extern "C" void kernel_launch(void* const* d_in, const int* in_sizes, int n_in,
                              void* d_out, int out_size, void* d_ws, size_t ws_size,
                              hipStream_t stream) {
  const float* xyz1 = (const float*)d_in[0];
  const float* xyz2 = (const float*)d_in[1];
  const float* points1 = (const float*)d_in[2];
  const float* points2 = (const float*)d_in[3];
  const float* W1 = (const float*)d_in[4];
  const float* b1 = (const float*)d_in[5];
  const float* W2 = (const float*)d_in[6];
  const float* b2 = (const float*)d_in[7];
  float* out = (float*)d_out;

  char* ws = (char*)d_ws;
  int* knn = (int*)ws;                        // 16384*16*4      = 1,048,576 B
  u16* p1t = (u16*)(ws + 1048576);            // 2,097,152 B
  u16* p2t = (u16*)(ws + 3145728);            // 2,097,152 B
  u16* W1b = (u16*)(ws + 5242880);            // 40,960 B
  u16* W2b = (u16*)(ws + 5283840);            // 32,768 B

  hipLaunchKernelGGL(transpose_cast, dim3(256), dim3(256), 0, stream, points1, p1t);
  hipLaunchKernelGGL(transpose_cast, dim3(256), dim3(256), 0, stream, points2, p2t);
  hipLaunchKernelGGL(prep_w, dim3(144), dim3(256), 0, stream, W1, W2, W1b, W2b);
  hipLaunchKernelGGL(knn_kernel, dim3(4096), dim3(256), 0, stream, xyz1, xyz2, knn);
  hipLaunchKernelGGL(mlp_kernel, dim3(2048), dim3(256), 0, stream,
                     xyz1, xyz2, p1t, p2t, knn, W1b, b1, W2b, b2, out);
}

// Round 6
// 267.993 us; speedup vs baseline: 1.2667x; 1.1782x over previous
//
#include <hip/hip_runtime.h>

typedef unsigned short u16;
typedef unsigned int u32;
typedef unsigned long long u64;
typedef __bf16 bf16x8 __attribute__((ext_vector_type(8)));
typedef float f32x4 __attribute__((ext_vector_type(4)));

#define MFMA16(a, b, c) __builtin_amdgcn_mfma_f32_16x16x32_bf16(a, b, c, 0, 0, 0)

static __device__ __forceinline__ u16 f2bf(float f) {
  union { float f; u32 u; } v; v.f = f;
  u32 u = v.u;
  u32 r = (u + 0x7FFFu + ((u >> 16) & 1u)) >> 16;  // RNE
  return (u16)r;
}

static __device__ __forceinline__ bf16x8 ld16(const u16* p) {
  return __builtin_bit_cast(bf16x8, *(const uint4*)p);
}

static __device__ __forceinline__ u64 u64min(u64 a, u64 b) { return a < b ? a : b; }

// In-wave bitonic sort of 64 u64 keys, ascending by lane. 21 compare-exchange levels.
static __device__ __forceinline__ u64 bitonic64(u64 v, int lane) {
#pragma unroll
  for (int k = 2; k <= 64; k <<= 1) {
#pragma unroll
    for (int j = k >> 1; j > 0; j >>= 1) {
      u64 o = __shfl_xor(v, j, 64);
      bool up = ((lane & k) == 0);
      bool lower = ((lane & j) == 0);
      u64 mn = v < o ? v : o;
      u64 mx = v < o ? o : v;
      v = (lower == up) ? mn : mx;
    }
  }
  return v;
}

// ---------------------------------------------------------------------------
// K2a: transpose+cast  src [B][64][4096] f32  ->  dst [B][4096][64] bf16
// ---------------------------------------------------------------------------
__global__ __launch_bounds__(256) void transpose_cast(const float* __restrict__ src,
                                                      u16* __restrict__ dst) {
  __shared__ __align__(4) u16 tile[64 * 66];
  const int t = threadIdx.x;
  const int b = blockIdx.x >> 6;
  const int n0 = (blockIdx.x & 63) << 6;
  const float* sp = src + ((size_t)b << 18);
#pragma unroll
  for (int i = 0; i < 16; i++) {
    int d = (i << 2) + (t >> 6);
    int n = t & 63;
    tile[n * 66 + d] = f2bf(sp[((size_t)d << 12) + n0 + n]);
  }
  __syncthreads();
  u16* dp = dst + ((size_t)(b * 4096 + n0) << 6);
#pragma unroll
  for (int i = 0; i < 8; i++) {
    int n = (i << 3) + (t >> 5);
    int dp2 = t & 31;
    *(u32*)(dp + n * 64 + (dp2 << 1)) = *(const u32*)(tile + n * 66 + (dp2 << 1));
  }
}

// ---------------------------------------------------------------------------
// K2b: cast/pad weights.  W1 [128][131] -> W1b [128][160] bf16 (zero pad),
// W2 [128][128] -> W2b bf16.
// ---------------------------------------------------------------------------
__global__ __launch_bounds__(256) void prep_w(const float* __restrict__ W1,
                                              const float* __restrict__ W2,
                                              u16* __restrict__ W1b,
                                              u16* __restrict__ W2b) {
  int t = blockIdx.x * 256 + threadIdx.x;
  if (t < 128 * 160) {
    int r = t / 160, c = t - r * 160;
    W1b[t] = (c < 131) ? f2bf(W1[r * 131 + c]) : (u16)0;
  } else {
    int u = t - 128 * 160;
    W2b[u] = f2bf(W2[u]);
  }
}

// ---------------------------------------------------------------------------
// K1: wave-per-row KNN-16, zero barriers.
// LESSON (round 5): keys must be computed EXACTLY ONCE — recomputing at a
// second code site gave different FP contraction and flipped near-ties.
// Here each key is computed once in pass 1 and stored to per-wave LDS
// (column layout j*64+lane: 2-way bank aliasing only = free). tau,
// compaction, and the final sort all consume the same stored bits.
// Distance arithmetic bit-exact to the round-3/4 passing kernels:
//   s1/s2 = ((a^2+b^2)+c^2) rn;  dot = fma(z,bz,fma(y,by,mul(x,bx)));
//   d2 = fl(fl(s1+s2) - fl(2*dot)); key = monotone_u32(d2); k64 = key<<32|m.
// Selection: per-lane top-1 -> bitonic-64 of heads -> tau = 16th head
// (provable upper bound on global 16th; keys unique so exactly 16 lanes
// contribute) -> compact k64 <= tau from LDS into surv (typically ~20,
// provably from <=16 lanes) -> bitonic-64 -> lanes 0..15 store.
// Cold path (S > 64, astronomically rare): exact increasing-order wave-min
// extraction straight from the LDS keys.
// ---------------------------------------------------------------------------
__global__ __launch_bounds__(256) void knn_kernel(const float* __restrict__ xyz1,
                                                  const float* __restrict__ xyz2,
                                                  int* __restrict__ knn) {
  __shared__ u32 keyL[4][4096];  // 64 KB: per-wave key store, [j*64 + lane]
  __shared__ u64 surv[4][64];    // 2 KB
  __shared__ u32 cnt[4];
  const int t = threadIdx.x;
  const int lane = t & 63;
  const int w = t >> 6;
  const int row = blockIdx.x * 4 + w;  // 0..16383
  const int b = row >> 12;
  const int n = row & 4095;
  const float* X1 = xyz1 + b * 12288;
  const float* X2 = xyz2 + b * 12288;
  const float x = X1[n];
  const float y = X1[4096 + n];
  const float z = X1[8192 + n];
  const float s1 = __fadd_rn(__fadd_rn(__fmul_rn(x, x), __fmul_rn(y, y)),
                             __fmul_rn(z, z));
  const int base = lane << 6;  // this lane's 64 contiguous candidates

  // ---- pass 1: compute keys ONCE, store to LDS, fold per-lane top-1 ------
  u64 head = ~0ull;
#pragma unroll
  for (int j = 0; j < 16; j++) {
    f32x4 bx = *(const f32x4*)(X2 + base + j * 4);
    f32x4 by = *(const f32x4*)(X2 + 4096 + base + j * 4);
    f32x4 bz = *(const f32x4*)(X2 + 8192 + base + j * 4);
#pragma unroll
    for (int e = 0; e < 4; e++) {
      float s2 = __fadd_rn(__fadd_rn(__fmul_rn(bx[e], bx[e]), __fmul_rn(by[e], by[e])),
                           __fmul_rn(bz[e], bz[e]));
      float dt = __builtin_fmaf(z, bz[e], __builtin_fmaf(y, by[e], __fmul_rn(x, bx[e])));
      float d2 = __fsub_rn(__fadd_rn(s1, s2), __fmul_rn(2.0f, dt));
      u32 bb = __float_as_uint(d2);
      u32 sgn = (u32)((int)bb >> 31);
      u32 key = bb ^ (sgn | 0x80000000u);  // monotone total order for floats
      keyL[w][(j * 4 + e) * 64 + lane] = key;
      u64 k64 = ((u64)key << 32) | (u32)(base + j * 4 + e);
      head = head < k64 ? head : k64;
    }
  }

  // tau = 16th smallest lane-head (valid upper bound on global 16th)
  u64 hs = bitonic64(head, lane);
  u64 tau = __shfl(hs, 15, 64);

  // ---- pass 2: re-read SAME key bits from LDS, compact k64 <= tau --------
  if (lane == 0) cnt[w] = 0;
#pragma unroll
  for (int j = 0; j < 64; j++) {
    u32 key = keyL[w][j * 64 + lane];
    u64 k64 = ((u64)key << 32) | (u32)(base + j);
    if (k64 <= tau) {
      u32 slot = atomicAdd(&cnt[w], 1u);
      if (slot < 64) surv[w][slot] = k64;  // order irrelevant: fully sorted below
    }
  }
  u32 S = cnt[w];  // same-wave LDS ops are in order: all adds visible

  if (S <= 64) {
    u64 v = (lane < (int)S) ? surv[w][lane] : ~0ull;
    v = bitonic64(v, lane);
    if (lane < 16) knn[row * 16 + lane] = (int)(v & 0xFFFFFFFFull);
  } else {
    // exact cold path: increasing-order extraction from the stored keys
    u64 prev = 0;
    for (int r = 0; r < 16; r++) {
      u64 lm = ~0ull;
#pragma unroll
      for (int j = 0; j < 64; j++) {
        u32 key = keyL[w][j * 64 + lane];
        u64 k64 = ((u64)key << 32) | (u32)(base + j);
        if (k64 > prev && k64 < lm) lm = k64;
      }
      u64 gm = lm;
#pragma unroll
      for (int off = 32; off; off >>= 1) gm = u64min(gm, __shfl_xor(gm, off, 64));
      if (lane == 0) knn[row * 16 + r] = (int)(gm & 0xFFFFFFFFull);
      prev = gm;
    }
  }
}

// ---------------------------------------------------------------------------
// K3: fused gather + MLP (bf16 MFMA) + inverse-distance weighted reduce.
// 8 query rows per block -> M = 128 k-points.  F in LDS [128][168] bf16.
// H1 overwrites F cols 0..127 (each wave owns its 32 rows end-to-end).
// ---------------------------------------------------------------------------
__global__ __launch_bounds__(256) void mlp_kernel(
    const float* __restrict__ xyz1, const float* __restrict__ xyz2,
    const u16* __restrict__ p1t, const u16* __restrict__ p2t,
    const int* __restrict__ knn,
    const u16* __restrict__ W1b, const float* __restrict__ b1,
    const u16* __restrict__ W2b, const float* __restrict__ b2,
    float* __restrict__ out) {
  __shared__ __align__(16) u16 F[128 * 168];
  __shared__ __align__(16) float winv[128];
  __shared__ __align__(16) float wnorm[128];
  __shared__ __align__(16) float outbuf[128 * 12];
  const int t = threadIdx.x;
  const int g = blockIdx.x;
  const int b = g >> 9;
  const int rbase = (g & 511) << 3;

  // ---- Phase A: build F = [p1 | p2[idx] | dir | 0-pad] --------------------
  {
    const int m = t >> 1, half = t & 1;
    const int n1 = rbase + (m >> 4);
    const uint4* s1p = (const uint4*)(p1t + ((size_t)(b * 4096 + n1) << 6)) + half * 4;
    uint4* d1p = (uint4*)(F + m * 168) + half * 4;
    d1p[0] = s1p[0]; d1p[1] = s1p[1]; d1p[2] = s1p[2]; d1p[3] = s1p[3];
    const int idx = knn[(((size_t)(b * 4096 + n1)) << 4) + (m & 15)];
    const uint4* s2p = (const uint4*)(p2t + ((size_t)(b * 4096 + idx) << 6)) + half * 4;
    uint4* d2p = (uint4*)(F + m * 168 + 64) + half * 4;
    d2p[0] = s2p[0]; d2p[1] = s2p[1]; d2p[2] = s2p[2]; d2p[3] = s2p[3];
  }
  if (t < 128) {
    const int m = t;
    const int n1 = rbase + (m >> 4);
    const int idx = knn[(((size_t)(b * 4096 + n1)) << 4) + (m & 15)];
    const float* X1 = xyz1 + b * 12288;
    const float* X2 = xyz2 + b * 12288;
    float dx = X2[idx] - X1[n1];
    float dy = X2[4096 + idx] - X1[4096 + n1];
    float dz = X2[8192 + idx] - X1[8192 + n1];
    u32 u0 = (u32)f2bf(dx) | ((u32)f2bf(dy) << 16);
    u32 u1 = (u32)f2bf(dz);
    uint4 pk = make_uint4(u0, u1, 0u, 0u);
    *(uint4*)(F + m * 168 + 128) = pk;
    float d = sqrtf(dx * dx + dy * dy + dz * dz);
    winv[m] = 1.0f / fmaxf(d, 1e-10f);
  } else {
    const int m = t - 128;
    uint4 zz = make_uint4(0u, 0u, 0u, 0u);
    uint4* zp = (uint4*)(F + m * 168 + 136);
    zp[0] = zz; zp[1] = zz; zp[2] = zz; zp[3] = zz;
  }
  __syncthreads();
  if (t < 128) {
    const int r = t >> 4;
    float s = 0.f;
#pragma unroll
    for (int k = 0; k < 16; k++) s += winv[(r << 4) + k];
    wnorm[t] = winv[t] / s;
  }
  __syncthreads();

  const int lane = t & 63;
  const int wid = t >> 6;
  const int l15 = lane & 15;
  const int quad = lane >> 4;
  const int koff = quad << 3;

  const u16* Fr0 = F + (wid * 32 + l15) * 168 + koff;
  const u16* Fr1 = Fr0 + 16 * 168;

  // ---- GEMM1: [128x160] x W1b^T -> H1 [128x128] ---------------------------
  f32x4 acc[2][8];
  const f32x4 z4 = {0.f, 0.f, 0.f, 0.f};
#pragma unroll
  for (int i = 0; i < 2; i++)
#pragma unroll
    for (int j = 0; j < 8; j++) acc[i][j] = z4;

#pragma unroll
  for (int s = 0; s < 5; s++) {
    bf16x8 a0 = ld16(Fr0 + s * 32);
    bf16x8 a1 = ld16(Fr1 + s * 32);
#pragma unroll
    for (int nt = 0; nt < 8; nt++) {
      bf16x8 bf = ld16(W1b + (nt * 16 + l15) * 160 + s * 32 + koff);
      acc[0][nt] = MFMA16(a0, bf, acc[0][nt]);
      acc[1][nt] = MFMA16(a1, bf, acc[1][nt]);
    }
  }
#pragma unroll
  for (int nt = 0; nt < 8; nt++) {
    const float bv = b1[nt * 16 + l15];
#pragma unroll
    for (int mt = 0; mt < 2; mt++) {
      u16* hrow = F + (wid * 32 + mt * 16 + quad * 4) * 168 + nt * 16 + l15;
#pragma unroll
      for (int r = 0; r < 4; r++) {
        float zv = acc[mt][nt][r] + bv;
        zv = (zv >= 0.f) ? zv : 0.1f * zv;
        hrow[r * 168] = f2bf(zv);
      }
    }
  }
  __syncthreads();

  // ---- GEMM2: H1 [128x128] x W2b^T ---------------------------------------
  f32x4 acc2[2][8];
#pragma unroll
  for (int i = 0; i < 2; i++)
#pragma unroll
    for (int j = 0; j < 8; j++) acc2[i][j] = z4;

#pragma unroll
  for (int s = 0; s < 4; s++) {
    bf16x8 a0 = ld16(Fr0 + s * 32);
    bf16x8 a1 = ld16(Fr1 + s * 32);
#pragma unroll
    for (int nt = 0; nt < 8; nt++) {
      bf16x8 bf = ld16(W2b + (nt * 16 + l15) * 128 + s * 32 + koff);
      acc2[0][nt] = MFMA16(a0, bf, acc2[0][nt]);
      acc2[1][nt] = MFMA16(a1, bf, acc2[1][nt]);
    }
  }
  // ---- epilogue: leaky + bias, weighted sum over k, transpose via LDS -----
#pragma unroll
  for (int mt = 0; mt < 2; mt++) {
    const int mrow = wid * 2 + mt;
    const f32x4 w4 = *(const f32x4*)&wnorm[(mrow << 4) + (quad << 2)];
#pragma unroll
    for (int nt = 0; nt < 8; nt++) {
      const float bv = b2[nt * 16 + l15];
      float p = 0.f;
#pragma unroll
      for (int r = 0; r < 4; r++) {
        float zv = acc2[mt][nt][r] + bv;
        zv = (zv >= 0.f) ? zv : 0.1f * zv;
        p += zv * w4[r];
      }
      p += __shfl_xor(p, 16);
      p += __shfl_xor(p, 32);
      if (quad == 0) outbuf[(nt * 16 + l15) * 12 + mrow] = p;
    }
  }
  __syncthreads();
  {
    const int ch = t >> 1, half = t & 1;
    f32x4 v = *(const f32x4*)&outbuf[ch * 12 + (half << 2)];
    float* op = out + (((size_t)(b * 128 + ch)) << 12) + rbase + (half << 2);
    *(f32x4*)op = v;
  }
}

// ---------------------------------------------------------------------------
extern "C" void kernel_launch(void* const* d_in, const int* in_sizes, int n_in,
                              void* d_out, int out_size, void* d_ws, size_t ws_size,
                              hipStream_t stream) {
  const float* xyz1 = (const float*)d_in[0];
  const float* xyz2 = (const float*)d_in[1];
  const float* points1 = (const float*)d_in[2];
  const float* points2 = (const float*)d_in[3];
  const float* W1 = (const float*)d_in[4];
  const float* b1 = (const float*)d_in[5];
  const float* W2 = (const float*)d_in[6];
  const float* b2 = (const float*)d_in[7];
  float* out = (float*)d_out;

  char* ws = (char*)d_ws;
  int* knn = (int*)ws;                        // 16384*16*4      = 1,048,576 B
  u16* p1t = (u16*)(ws + 1048576);            // 2,097,152 B
  u16* p2t = (u16*)(ws + 3145728);            // 2,097,152 B
  u16* W1b = (u16*)(ws + 5242880);            // 40,960 B
  u16* W2b = (u16*)(ws + 5283840);            // 32,768 B

  hipLaunchKernelGGL(transpose_cast, dim3(256), dim3(256), 0, stream, points1, p1t);
  hipLaunchKernelGGL(transpose_cast, dim3(256), dim3(256), 0, stream, points2, p2t);
  hipLaunchKernelGGL(prep_w, dim3(144), dim3(256), 0, stream, W1, W2, W1b, W2b);
  hipLaunchKernelGGL(knn_kernel, dim3(4096), dim3(256), 0, stream, xyz1, xyz2, knn);
  hipLaunchKernelGGL(mlp_kernel, dim3(2048), dim3(256), 0, stream,
                     xyz1, xyz2, p1t, p2t, knn, W1b, b1, W2b, b2, out);
}